// Round 13
// baseline (184.209 us; speedup 1.0000x reference)
//
#include <hip/hip_runtime.h>
#include <stdint.h>
#include <math.h>

typedef __bf16 bf16x8 __attribute__((ext_vector_type(8)));
typedef float f32x16 __attribute__((ext_vector_type(16)));
typedef unsigned short u16x8 __attribute__((ext_vector_type(8)));

__device__ __forceinline__ unsigned short f32_to_bf16_rne(float f) {
    unsigned u = __builtin_bit_cast(unsigned, f);
    u += 0x7fffu + ((u >> 16) & 1u);
    return (unsigned short)(u >> 16);
}

// ---------------------------------------------------------------------------
// int8 symmetric group-wise fake-quant, group 128 along contiguous axis.
// 32 lanes per group, one float4 per lane. Output = bf16(q*scale).
// At HBM BW roofline — unchanged.
// ---------------------------------------------------------------------------
__global__ __launch_bounds__(256) void quant_fake_int8_kernel(
    const float* __restrict__ in, unsigned short* __restrict__ out,
    long long n) {
    long long t = (long long)blockIdx.x * 256 + threadIdx.x;
    long long base = t * 4;
    if (base >= n) return;
    const float4 v = *reinterpret_cast<const float4*>(in + base);
    float m = fmaxf(fmaxf(fabsf(v.x), fabsf(v.y)),
                    fmaxf(fabsf(v.z), fabsf(v.w)));
#pragma unroll
    for (int off = 1; off <= 16; off <<= 1)
        m = fmaxf(m, __shfl_xor(m, off, 64));
    const float scale = fmaxf(m / 127.0f, 1e-8f);
    const float d0 = fminf(fmaxf(rintf(v.x / scale), -128.0f), 127.0f) * scale;
    const float d1 = fminf(fmaxf(rintf(v.y / scale), -128.0f), 127.0f) * scale;
    const float d2 = fminf(fmaxf(rintf(v.z / scale), -128.0f), 127.0f) * scale;
    const float d3 = fminf(fmaxf(rintf(v.w / scale), -128.0f), 127.0f) * scale;
    ushort4 o;
    o.x = f32_to_bf16_rne(d0);
    o.y = f32_to_bf16_rne(d1);
    o.z = f32_to_bf16_rne(d2);
    o.w = f32_to_bf16_rne(d3);
    *reinterpret_cast<ushort4*>(out + base) = o;
}

// ---------------------------------------------------------------------------
// 256x256 bf16 GEMM — round-9 structure (quadrant tail-barrier phases,
// A ring-3 + B dbuf-2 = 160 KB, counted vmcnt) with 32x32x16 MFMA.
// C[M][N] = A[M][K] * B[N][K]^T. 512 thr = 8 waves (2M x 4N), wave 128x64 =
// 4 m-blocks x 2 n-blocks of 32x32; K-tile 64 = 4 k-steps of 16.
// 32 MFMA/wave/tile (vs 64 of 16x16x32): measured shape ceiling 2495 TF vs
// 2075-2176 -> MFMA floor 2483 -> 2066 cyc/tile; reads unchanged (24 x b128).
//
// Fragment layouts (32x32x16_bf16):
//   A/B input: row = lane&31, k = (lane>>5)*8 + i  (8 bf16, 4 VGPR)
//   C/D:       col = lane&31, row = (reg&3) + 8*(reg>>2) + 4*(lane>>5)
// Phases per K-tile kt (tail-only barriers, NO lgkm pins — round-9 best):
//   P1: read A mb0,mb1 x4ks [8] + B nb0 x4ks [4]; stage B(kt+1)h0; 8 MFMA
//   P2: read B nb1 x4ks [4];                      stage B(kt+1)h1; 8 MFMA
//   P3: read A mb2,mb3 x4ks [8];                  stage A(kt+2)h0; 8 MFMA
//   P4: 0 reads;                                  stage A(kt+2)h1; 8 MFMA
//       boundary vmcnt(4); barrier.
// vmcnt ledger (2 gloads per stage_half, in-order): entering kt boundary:
// [B(kt+1) 4][A(kt+2) 4] -> vmcnt(4) drains A(kt+1)+B(kt+1) transitively,
// keeps A(kt+2) in flight. Prologue A0,B0,A1 -> vmcnt(4). Tail: NT-2 ->
// vmcnt(0). WAR: every staged region >= 3 tail barriers after last reader
// (round-9 audit). Swizzle (128B rows): colbyte ^ ((row&7)<<4) on
// pre-swizzled global source + swizzled read addr; for the 32x32 read,
// 16-lane quarter-waves hit 8 slots x 2 rows = 2-way = free (same as r9).
// ---------------------------------------------------------------------------
#define BM 256
#define BN 256
#define NSLOT 16384  // elems per 32 KB slot ([256][64] bf16)

__device__ __forceinline__ void gload16(const unsigned short* g,
                                        unsigned short* l) {
    __builtin_amdgcn_global_load_lds(
        (const __attribute__((address_space(1))) void*)(g),
        (__attribute__((address_space(3))) void*)(l), 16, 0, 0);
}

// Stage one half (rows h*128 .. h*128+127) of a [256][64] tile: 2 loads.
__device__ __forceinline__ void stage_half(const unsigned short* __restrict__ G,
                                           unsigned short* L, int tid,
                                           int baseRow, int K, int k0, int h) {
    const int srow = tid >> 3;                                   // 0..63
    const int scb = (((tid & 7) << 4) ^ ((srow & 7) << 4)) >> 1; // elem col
#pragma unroll
    for (int i = 2 * h; i < 2 * h + 2; ++i)
        gload16(G + (size_t)(baseRow + i * 64 + srow) * K + k0 + scb,
                L + i * 4096 + (tid >> 6) * 512);
}

#define LDF(BASE, ROW, COE)                                      \
    __builtin_bit_cast(bf16x8, *reinterpret_cast<const u16x8*>(  \
                                   (BASE) + (((ROW) << 6) + (COE))))
#define MFMA32(a, bb, c) \
    __builtin_amdgcn_mfma_f32_32x32x16_bf16(a, bb, c, 0, 0, 0)

__global__ __launch_bounds__(512, 2) void gemm_bf16_q32(
    const unsigned short* __restrict__ A,  // [M][K] bf16 bits
    const unsigned short* __restrict__ B,  // [N][K] bf16 bits
    float* __restrict__ C,                 // [M][N]
    int M, int N, int K) {
    __shared__ __align__(16) unsigned short smem[5 * NSLOT];  // 160 KB

    const int tid = threadIdx.x;
    const int lane = tid & 63;
    const int wid = tid >> 6;
    const int wr = wid >> 2;  // 0..1  (M half)
    const int wc = wid & 3;   // 0..3  (N quarter)
    const int l31 = lane & 31;
    const int lkh = lane >> 5;        // 0..1 = k-half of 16B frag
    const int swzb = (l31 & 7) << 4;  // byte swizzle from frag row
    // elem col of k-step ks: ((ks*32 + lkh*16) ^ swzb) >> 1
    const int coe0 = ((0 + lkh * 16) ^ swzb) >> 1;
    const int coe1 = ((32 + lkh * 16) ^ swzb) >> 1;
    const int coe2 = ((64 + lkh * 16) ^ swzb) >> 1;
    const int coe3 = ((96 + lkh * 16) ^ swzb) >> 1;
    const int ra = wr * 128 + l31;  // + mb*32  (A row in tile)
    const int rb = wc * 64 + l31;   // + nb*32  (B row in tile)

    // XCD-chunked bijective remap over 512 blocks (512 % 8 == 0).
    const int id = (blockIdx.x & 7) * 64 + (blockIdx.x >> 3);
    const int tileN = (id & 7) * BN;
    const int tileM = (id >> 3) * BM;

    const int NT = K >> 6;  // 32

    f32x16 acc[4][2] = {};

    // A-ring pointers (rotate each tile), B dbuf pointers (swap each tile).
    unsigned short* pa0 = smem + 0 * NSLOT;  // A(kt)
    unsigned short* pa1 = smem + 1 * NSLOT;  // A(kt+1)
    unsigned short* pa2 = smem + 2 * NSLOT;  // A(kt+2) staging target
    unsigned short* pb0 = smem + 3 * NSLOT;  // B(kt)
    unsigned short* pb1 = smem + 4 * NSLOT;  // B(kt+1) staging target

    // ---- prologue: A0, B0, A1 (12 loads); drain A0+B0; keep A1 in flight.
    stage_half(A, pa0, tid, tileM, K, 0, 0);
    stage_half(A, pa0, tid, tileM, K, 0, 1);
    stage_half(B, pb0, tid, tileN, K, 0, 0);
    stage_half(B, pb0, tid, tileN, K, 0, 1);
    stage_half(A, pa1, tid, tileM, K, 64, 0);
    stage_half(A, pa1, tid, tileM, K, 64, 1);
    asm volatile("s_waitcnt vmcnt(4)" ::: "memory");
    __builtin_amdgcn_s_barrier();

#pragma unroll 1
    for (int kt = 0; kt < NT; ++kt) {
        const unsigned short* Ab = pa0;
        const unsigned short* Bb = pb0;
        const int k1 = (kt + 1) << 6;
        const int k2 = (kt + 2) << 6;
        const bool pfB = (kt + 1 < NT);
        const bool pfA = (kt + 2 < NT);

        // ---- P1: A mb0,mb1 (4 ks each) + B nb0 (4 ks); Q(mb0-1, nb0) ----
        bf16x8 a00 = LDF(Ab, ra + 0, coe0), a01 = LDF(Ab, ra + 0, coe1);
        bf16x8 a02 = LDF(Ab, ra + 0, coe2), a03 = LDF(Ab, ra + 0, coe3);
        bf16x8 a10 = LDF(Ab, ra + 32, coe0), a11 = LDF(Ab, ra + 32, coe1);
        bf16x8 a12 = LDF(Ab, ra + 32, coe2), a13 = LDF(Ab, ra + 32, coe3);
        bf16x8 b00 = LDF(Bb, rb + 0, coe0), b01 = LDF(Bb, rb + 0, coe1);
        bf16x8 b02 = LDF(Bb, rb + 0, coe2), b03 = LDF(Bb, rb + 0, coe3);
        if (pfB) stage_half(B, pb1, tid, tileN, K, k1, 0);
        __builtin_amdgcn_s_setprio(1);
        acc[0][0] = MFMA32(a03, b03, MFMA32(a02, b02,
                    MFMA32(a01, b01, MFMA32(a00, b00, acc[0][0]))));
        acc[1][0] = MFMA32(a13, b03, MFMA32(a12, b02,
                    MFMA32(a11, b01, MFMA32(a10, b00, acc[1][0]))));
        __builtin_amdgcn_s_setprio(0);
        __builtin_amdgcn_s_barrier();

        // ---- P2: B nb1 (4 ks); Q(mb0-1, nb1) ----
        bf16x8 b10 = LDF(Bb, rb + 32, coe0), b11 = LDF(Bb, rb + 32, coe1);
        bf16x8 b12 = LDF(Bb, rb + 32, coe2), b13 = LDF(Bb, rb + 32, coe3);
        if (pfB) stage_half(B, pb1, tid, tileN, K, k1, 1);
        __builtin_amdgcn_s_setprio(1);
        acc[0][1] = MFMA32(a03, b13, MFMA32(a02, b12,
                    MFMA32(a01, b11, MFMA32(a00, b10, acc[0][1]))));
        acc[1][1] = MFMA32(a13, b13, MFMA32(a12, b12,
                    MFMA32(a11, b11, MFMA32(a10, b10, acc[1][1]))));
        __builtin_amdgcn_s_setprio(0);
        __builtin_amdgcn_s_barrier();

        // ---- P3: A mb2,mb3 (4 ks each); Q(mb2-3, nb1) ----
        bf16x8 c00 = LDF(Ab, ra + 64, coe0), c01 = LDF(Ab, ra + 64, coe1);
        bf16x8 c02 = LDF(Ab, ra + 64, coe2), c03 = LDF(Ab, ra + 64, coe3);
        bf16x8 c10 = LDF(Ab, ra + 96, coe0), c11 = LDF(Ab, ra + 96, coe1);
        bf16x8 c12 = LDF(Ab, ra + 96, coe2), c13 = LDF(Ab, ra + 96, coe3);
        if (pfA) stage_half(A, pa2, tid, tileM, K, k2, 0);
        __builtin_amdgcn_s_setprio(1);
        acc[2][1] = MFMA32(c03, b13, MFMA32(c02, b12,
                    MFMA32(c01, b11, MFMA32(c00, b10, acc[2][1]))));
        acc[3][1] = MFMA32(c13, b13, MFMA32(c12, b12,
                    MFMA32(c11, b11, MFMA32(c10, b10, acc[3][1]))));
        __builtin_amdgcn_s_setprio(0);
        __builtin_amdgcn_s_barrier();

        // ---- P4: 0 reads; Q(mb2-3, nb0); boundary vmcnt ----
        if (pfA) stage_half(A, pa2, tid, tileM, K, k2, 1);
        __builtin_amdgcn_s_setprio(1);
        acc[2][0] = MFMA32(c03, b03, MFMA32(c02, b02,
                    MFMA32(c01, b01, MFMA32(c00, b00, acc[2][0]))));
        acc[3][0] = MFMA32(c13, b03, MFMA32(c12, b02,
                    MFMA32(c11, b01, MFMA32(c10, b00, acc[3][0]))));
        __builtin_amdgcn_s_setprio(0);
        if (pfA)
            asm volatile("s_waitcnt vmcnt(4)" ::: "memory");
        else if (pfB)
            asm volatile("s_waitcnt vmcnt(0)" ::: "memory");
        __builtin_amdgcn_s_barrier();

        // rotate A ring, swap B dbuf
        unsigned short* t = pa0;
        pa0 = pa1;
        pa1 = pa2;
        pa2 = t;
        t = pb0;
        pb0 = pb1;
        pb1 = t;
    }

    // ---- epilogue: 32x32 C/D layout col = lane&31,
    //      row = (reg&3) + 8*(reg>>2) + 4*(lane>>5) ----
    const int c0 = tileN + wc * 64 + l31;
    const int r0 = tileM + wr * 128 + lkh * 4;
#pragma unroll
    for (int mb = 0; mb < 4; ++mb)
#pragma unroll
        for (int nb = 0; nb < 2; ++nb)
#pragma unroll
            for (int r = 0; r < 16; ++r)
                C[(size_t)(r0 + mb * 32 + (r & 3) + 8 * (r >> 2)) * N +
                  (c0 + nb * 32)] = acc[mb][nb][r];
}

// ---------------------------------------------------------------------------
extern "C" void kernel_launch(void* const* d_in, const int* in_sizes, int n_in,
                              void* d_out, int out_size, void* d_ws,
                              size_t ws_size, hipStream_t stream) {
    const float* x = (const float*)d_in[0];  // [B,S,IN]  f32
    const float* w = (const float*)d_in[1];  // [OUT,IN]  f32
    float* out = (float*)d_out;              // [B,S,OUT] f32

    const long long MK = (long long)in_sizes[0];
    const long long NK = (long long)in_sizes[1];
    const long long MN = (long long)out_size;
    const long long K =
        (long long)(sqrt((double)MK * (double)NK / (double)MN) + 0.5);
    const long long M = MK / K;  // 16384
    const long long N = NK / K;  // 2048

    unsigned short* qx = (unsigned short*)d_ws;  // M*K bf16
    unsigned short* qw = qx + MK;                // N*K bf16

    quant_fake_int8_kernel<<<(int)(MK / 1024), 256, 0, stream>>>(x, qx, MK);
    quant_fake_int8_kernel<<<(int)(NK / 1024), 256, 0, stream>>>(w, qw, NK);

    dim3 grid((int)((M / BM) * (N / BN)));  // 64 * 8 = 512
    gemm_bf16_q32<<<grid, 512, 0, stream>>>(qx, qw, out, (int)M, (int)N,
                                            (int)K);
}

// Round 14
// 168.905 us; speedup vs baseline: 1.0906x; 1.0906x over previous
//
#include <hip/hip_runtime.h>
#include <stdint.h>
#include <math.h>

typedef __bf16 bf16x8 __attribute__((ext_vector_type(8)));
typedef float f32x4 __attribute__((ext_vector_type(4)));
typedef unsigned short u16x8 __attribute__((ext_vector_type(8)));

__device__ __forceinline__ unsigned short f32_to_bf16_rne(float f) {
    unsigned u = __builtin_bit_cast(unsigned, f);
    u += 0x7fffu + ((u >> 16) & 1u);
    return (unsigned short)(u >> 16);
}

// ---------------------------------------------------------------------------
// Fused int8 group-wise fake-quant for BOTH tensors in one dispatch.
// Group 128 along contiguous axis; 32 lanes/group, one float4/lane;
// output bf16(q*scale). nx % 256 == 0, so a wave never straddles the x/w
// boundary and each 32-lane half-wave stays within one group of one tensor.
// ---------------------------------------------------------------------------
__global__ __launch_bounds__(256) void quant_fake_int8_fused(
    const float* __restrict__ x, const float* __restrict__ w,
    unsigned short* __restrict__ qx, unsigned short* __restrict__ qw,
    long long nx, long long nw) {
    long long t = (long long)blockIdx.x * 256 + threadIdx.x;
    long long base = t * 4;
    const float* in;
    unsigned short* out;
    if (base < nx) {
        in = x;
        out = qx;
    } else {
        base -= nx;
        if (base >= nw) return;
        in = w;
        out = qw;
    }
    const float4 v = *reinterpret_cast<const float4*>(in + base);
    float m = fmaxf(fmaxf(fabsf(v.x), fabsf(v.y)),
                    fmaxf(fabsf(v.z), fabsf(v.w)));
#pragma unroll
    for (int off = 1; off <= 16; off <<= 1)
        m = fmaxf(m, __shfl_xor(m, off, 64));
    const float scale = fmaxf(m / 127.0f, 1e-8f);
    const float d0 = fminf(fmaxf(rintf(v.x / scale), -128.0f), 127.0f) * scale;
    const float d1 = fminf(fmaxf(rintf(v.y / scale), -128.0f), 127.0f) * scale;
    const float d2 = fminf(fmaxf(rintf(v.z / scale), -128.0f), 127.0f) * scale;
    const float d3 = fminf(fmaxf(rintf(v.w / scale), -128.0f), 127.0f) * scale;
    ushort4 o;
    o.x = f32_to_bf16_rne(d0);
    o.y = f32_to_bf16_rne(d1);
    o.z = f32_to_bf16_rne(d2);
    o.w = f32_to_bf16_rne(d3);
    *reinterpret_cast<ushort4*>(out + base) = o;
}

// ---------------------------------------------------------------------------
// 256x256 bf16 GEMM, BK=64, QUADRANT phases with TAIL-ONLY barriers.
// (Round-9 verified optimum: 131.5 us, MfmaUtil 45.4%, 0 bank conflicts.)
// C[M][N] = A[M][K] * B[N][K]^T. 512 thr = 8 waves (2M x 4N), wave 128x64.
//
// Per K-tile kt, 4 phases; phase = {ds_reads; stage 2 gloads; setprio(1);
// 16 MFMA (one C-quadrant, K=64); setprio(0); s_barrier}.  NO head barrier,
// NO asm lgkmcnt, NO sched_barrier: compiler emits fine-grained counted
// lgkm waits, so a wave's MFMAs start as operands land while other waves'
// reads still drain (bounded-skew overlap).
//   P1: read A(m0-3)x2kk [8] + B(n0-1)x2kk [4]; stage B(kt+1)h0; Q(m0-3,n0-1)
//   P2: read B(n2-3)x2kk [4];                   stage B(kt+1)h1; Q(m0-3,n2-3)
//   P3: read A(m4-7)x2kk [8];                   stage A(kt+2)h0; Q(m4-7,n2-3)
//   P4: (0 reads);                              stage A(kt+2)h1; Q(m4-7,n0-1)
//       then boundary vmcnt + tail barrier.
//
// LDS: A ring-3 (3x32KB) + B dbuf-2 (2x32KB) = 160 KB, 1 block/CU.
// vmcnt ledger (2 gloads per stage_half, in-order queue): entering kt's
// boundary: [B(kt+1) 4][A(kt+2) 4] (A(kt+1) older, drained transitively) ->
// vmcnt(4) drains A(kt+1)+B(kt+1), keeps A(kt+2) in flight.
// Prologue: A0,B0,A1 (12 loads) -> vmcnt(4). Tail: kt==NT-2 -> vmcnt(0).
// WAR audit (skew <= 1 phase, barriers every phase):
//   * stage B(kt+1) slot: last read = tile kt-1 P2 (>=3 barriers earlier).
//   * stage A(kt+2) slot (kt-1)%3: last read = tile kt-1 P3 (>=4 barriers).
// Swizzle (128B rows): colbyte ^ ((row&7)<<4) on pre-swizzled global source
// + swizzled read address (both-sides). Measured 0 conflicts (r2,8,9,12);
// NOTE: balanced only for 16-row-period reads — 32-row-period (32x32 MFMA
// frags) measured 1.26e7 conflicts (r13). Keep 16x16 fragments.
// ---------------------------------------------------------------------------
#define BM 256
#define BN 256
#define NSLOT 16384  // elems per 32 KB slot ([256][64] bf16)

__device__ __forceinline__ void gload16(const unsigned short* g,
                                        unsigned short* l) {
    __builtin_amdgcn_global_load_lds(
        (const __attribute__((address_space(1))) void*)(g),
        (__attribute__((address_space(3))) void*)(l), 16, 0, 0);
}

// Stage one half (rows h*128 .. h*128+127) of a [256][64] tile: 2 loads.
__device__ __forceinline__ void stage_half(const unsigned short* __restrict__ G,
                                           unsigned short* L, int tid,
                                           int baseRow, int K, int k0, int h) {
    const int srow = tid >> 3;                                   // 0..63
    const int scb = (((tid & 7) << 4) ^ ((srow & 7) << 4)) >> 1; // elem col
#pragma unroll
    for (int i = 2 * h; i < 2 * h + 2; ++i)
        gload16(G + (size_t)(baseRow + i * 64 + srow) * K + k0 + scb,
                L + i * 4096 + (tid >> 6) * 512);
}

#define LDF(BASE, ROW, COE)                                      \
    __builtin_bit_cast(bf16x8, *reinterpret_cast<const u16x8*>(  \
                                   (BASE) + (((ROW) << 6) + (COE))))
#define MFMA(a, bb, c) __builtin_amdgcn_mfma_f32_16x16x32_bf16(a, bb, c, 0, 0, 0)

__global__ __launch_bounds__(512, 2) void gemm_bf16_quad(
    const unsigned short* __restrict__ A,  // [M][K] bf16 bits
    const unsigned short* __restrict__ B,  // [N][K] bf16 bits
    float* __restrict__ C,                 // [M][N]
    int M, int N, int K) {
    __shared__ __align__(16) unsigned short smem[5 * NSLOT];  // 160 KB

    const int tid = threadIdx.x;
    const int lane = tid & 63;
    const int wid = tid >> 6;
    const int wr = wid >> 2;  // 0..1  (M half)
    const int wc = wid & 3;   // 0..3  (N quarter)
    const int l15 = lane & 15;
    const int lh = lane >> 4;
    const int swz = (lane & 7) << 4;
    const int coe0 = ((lh << 4) ^ swz) >> 1;        // kk=0 elem col
    const int coe1 = (((lh << 4) | 64) ^ swz) >> 1; // kk=1 elem col
    const int ra = wr * 128 + l15;                  // + m*16
    const int rb = wc * 64 + l15;                   // + n*16

    // XCD-chunked bijective remap over 512 blocks (512 % 8 == 0).
    const int id = (blockIdx.x & 7) * 64 + (blockIdx.x >> 3);
    const int tileN = (id & 7) * BN;
    const int tileM = (id >> 3) * BM;

    const int NT = K >> 6;  // 32

    f32x4 acc[8][4] = {};

    // A-ring pointers (rotate each tile), B dbuf pointers (swap each tile).
    unsigned short* pa0 = smem + 0 * NSLOT;  // A(kt)
    unsigned short* pa1 = smem + 1 * NSLOT;  // A(kt+1)
    unsigned short* pa2 = smem + 2 * NSLOT;  // A(kt+2) staging target
    unsigned short* pb0 = smem + 3 * NSLOT;  // B(kt)
    unsigned short* pb1 = smem + 4 * NSLOT;  // B(kt+1) staging target

    // ---- prologue: A0, B0, A1 (12 loads); drain A0+B0; keep A1 in flight.
    stage_half(A, pa0, tid, tileM, K, 0, 0);
    stage_half(A, pa0, tid, tileM, K, 0, 1);
    stage_half(B, pb0, tid, tileN, K, 0, 0);
    stage_half(B, pb0, tid, tileN, K, 0, 1);
    stage_half(A, pa1, tid, tileM, K, 64, 0);
    stage_half(A, pa1, tid, tileM, K, 64, 1);
    asm volatile("s_waitcnt vmcnt(4)" ::: "memory");
    __builtin_amdgcn_s_barrier();

#pragma unroll 1
    for (int kt = 0; kt < NT; ++kt) {
        const unsigned short* Ab = pa0;
        const unsigned short* Bb = pb0;
        const int k1 = (kt + 1) << 6;
        const int k2 = (kt + 2) << 6;
        const bool pfB = (kt + 1 < NT);
        const bool pfA = (kt + 2 < NT);

        // ---------- P1: A m0-3 (both kk) + B n0-1 (both kk); Q(0,0) -------
        bf16x8 a00 = LDF(Ab, ra + 0, coe0), a10 = LDF(Ab, ra + 16, coe0);
        bf16x8 a20 = LDF(Ab, ra + 32, coe0), a30 = LDF(Ab, ra + 48, coe0);
        bf16x8 a01 = LDF(Ab, ra + 0, coe1), a11 = LDF(Ab, ra + 16, coe1);
        bf16x8 a21 = LDF(Ab, ra + 32, coe1), a31 = LDF(Ab, ra + 48, coe1);
        bf16x8 b00 = LDF(Bb, rb + 0, coe0), b10 = LDF(Bb, rb + 16, coe0);
        bf16x8 b01 = LDF(Bb, rb + 0, coe1), b11 = LDF(Bb, rb + 16, coe1);
        if (pfB) stage_half(B, pb1, tid, tileN, K, k1, 0);
        __builtin_amdgcn_s_setprio(1);
        acc[0][0] = MFMA(a01, b01, MFMA(a00, b00, acc[0][0]));
        acc[1][0] = MFMA(a11, b01, MFMA(a10, b00, acc[1][0]));
        acc[2][0] = MFMA(a21, b01, MFMA(a20, b00, acc[2][0]));
        acc[3][0] = MFMA(a31, b01, MFMA(a30, b00, acc[3][0]));
        acc[0][1] = MFMA(a01, b11, MFMA(a00, b10, acc[0][1]));
        acc[1][1] = MFMA(a11, b11, MFMA(a10, b10, acc[1][1]));
        acc[2][1] = MFMA(a21, b11, MFMA(a20, b10, acc[2][1]));
        acc[3][1] = MFMA(a31, b11, MFMA(a30, b10, acc[3][1]));
        __builtin_amdgcn_s_setprio(0);
        __builtin_amdgcn_s_barrier();

        // ---------- P2: B n2-3 (both kk); Q(0,1) --------------------------
        bf16x8 b20 = LDF(Bb, rb + 32, coe0), b30 = LDF(Bb, rb + 48, coe0);
        bf16x8 b21 = LDF(Bb, rb + 32, coe1), b31 = LDF(Bb, rb + 48, coe1);
        if (pfB) stage_half(B, pb1, tid, tileN, K, k1, 1);
        __builtin_amdgcn_s_setprio(1);
        acc[0][2] = MFMA(a01, b21, MFMA(a00, b20, acc[0][2]));
        acc[1][2] = MFMA(a11, b21, MFMA(a10, b20, acc[1][2]));
        acc[2][2] = MFMA(a21, b21, MFMA(a20, b20, acc[2][2]));
        acc[3][2] = MFMA(a31, b21, MFMA(a30, b20, acc[3][2]));
        acc[0][3] = MFMA(a01, b31, MFMA(a00, b30, acc[0][3]));
        acc[1][3] = MFMA(a11, b31, MFMA(a10, b30, acc[1][3]));
        acc[2][3] = MFMA(a21, b31, MFMA(a20, b30, acc[2][3]));
        acc[3][3] = MFMA(a31, b31, MFMA(a30, b30, acc[3][3]));
        __builtin_amdgcn_s_setprio(0);
        __builtin_amdgcn_s_barrier();

        // ---------- P3: A m4-7 (both kk); Q(1,1) --------------------------
        bf16x8 c00 = LDF(Ab, ra + 64, coe0), c10 = LDF(Ab, ra + 80, coe0);
        bf16x8 c20 = LDF(Ab, ra + 96, coe0), c30 = LDF(Ab, ra + 112, coe0);
        bf16x8 c01 = LDF(Ab, ra + 64, coe1), c11 = LDF(Ab, ra + 80, coe1);
        bf16x8 c21 = LDF(Ab, ra + 96, coe1), c31 = LDF(Ab, ra + 112, coe1);
        if (pfA) stage_half(A, pa2, tid, tileM, K, k2, 0);
        __builtin_amdgcn_s_setprio(1);
        acc[4][2] = MFMA(c01, b21, MFMA(c00, b20, acc[4][2]));
        acc[5][2] = MFMA(c11, b21, MFMA(c10, b20, acc[5][2]));
        acc[6][2] = MFMA(c21, b21, MFMA(c20, b20, acc[6][2]));
        acc[7][2] = MFMA(c31, b21, MFMA(c30, b20, acc[7][2]));
        acc[4][3] = MFMA(c01, b31, MFMA(c00, b30, acc[4][3]));
        acc[5][3] = MFMA(c11, b31, MFMA(c10, b30, acc[5][3]));
        acc[6][3] = MFMA(c21, b31, MFMA(c20, b30, acc[6][3]));
        acc[7][3] = MFMA(c31, b31, MFMA(c30, b30, acc[7][3]));
        __builtin_amdgcn_s_setprio(0);
        __builtin_amdgcn_s_barrier();

        // ---------- P4: 0 reads; Q(1,0); boundary vmcnt -------------------
        if (pfA) stage_half(A, pa2, tid, tileM, K, k2, 1);
        __builtin_amdgcn_s_setprio(1);
        acc[4][0] = MFMA(c01, b01, MFMA(c00, b00, acc[4][0]));
        acc[5][0] = MFMA(c11, b01, MFMA(c10, b00, acc[5][0]));
        acc[6][0] = MFMA(c21, b01, MFMA(c20, b00, acc[6][0]));
        acc[7][0] = MFMA(c31, b01, MFMA(c30, b00, acc[7][0]));
        acc[4][1] = MFMA(c01, b11, MFMA(c00, b10, acc[4][1]));
        acc[5][1] = MFMA(c11, b11, MFMA(c10, b10, acc[5][1]));
        acc[6][1] = MFMA(c21, b11, MFMA(c20, b10, acc[6][1]));
        acc[7][1] = MFMA(c31, b11, MFMA(c30, b10, acc[7][1]));
        __builtin_amdgcn_s_setprio(0);
        if (pfA)
            asm volatile("s_waitcnt vmcnt(4)" ::: "memory");
        else if (pfB)
            asm volatile("s_waitcnt vmcnt(0)" ::: "memory");
        __builtin_amdgcn_s_barrier();

        // rotate A ring, swap B dbuf
        unsigned short* t = pa0;
        pa0 = pa1;
        pa1 = pa2;
        pa2 = t;
        t = pb0;
        pb0 = pb1;
        pb1 = t;
    }

    // ---- epilogue: C/D layout col = lane&15, row = (lane>>4)*4 + reg ----
    const int c0 = tileN + wc * 64 + l15;
    const int r0 = tileM + wr * 128 + lh * 4;
#pragma unroll
    for (int m = 0; m < 8; ++m)
#pragma unroll
        for (int n = 0; n < 4; ++n)
#pragma unroll
            for (int r = 0; r < 4; ++r)
                C[(size_t)(r0 + m * 16 + r) * N + (c0 + n * 16)] =
                    acc[m][n][r];
}

// ---------------------------------------------------------------------------
extern "C" void kernel_launch(void* const* d_in, const int* in_sizes, int n_in,
                              void* d_out, int out_size, void* d_ws,
                              size_t ws_size, hipStream_t stream) {
    const float* x = (const float*)d_in[0];  // [B,S,IN]  f32
    const float* w = (const float*)d_in[1];  // [OUT,IN]  f32
    float* out = (float*)d_out;              // [B,S,OUT] f32

    const long long MK = (long long)in_sizes[0];
    const long long NK = (long long)in_sizes[1];
    const long long MN = (long long)out_size;
    const long long K =
        (long long)(sqrt((double)MK * (double)NK / (double)MN) + 0.5);
    const long long M = MK / K;  // 16384
    const long long N = NK / K;  // 2048

    unsigned short* qx = (unsigned short*)d_ws;  // M*K bf16
    unsigned short* qw = qx + MK;                // N*K bf16

    // single fused quant dispatch for both tensors
    const long long total = MK + NK;
    quant_fake_int8_fused<<<(int)(total / 1024), 256, 0, stream>>>(
        x, w, qx, qw, MK, NK);

    dim3 grid((int)((M / BM) * (N / BN)));  // 64 * 8 = 512
    gemm_bf16_quad<<<grid, 512, 0, stream>>>(qx, qw, out, (int)M, (int)N,
                                             (int)K);
}